// Round 1
// baseline (2836.285 us; speedup 1.0000x reference)
//
#include <hip/hip_runtime.h>
#include <math.h>

#define N_NODES 100000
#define N_EDGES 1600000
#define D 64
#define TWO_D 128
#define LN_EPS 1e-5f

// ---------------------------------------------------------------------------
// Edge kernel: rel = x[src] - x[dst], max-scatter positive values into agg.
// agg is pre-zeroed; since reference does max(segment_max, 0), negative rel
// can never affect the result, so we only push rel > 0. For non-negative
// floats, integer compare == float compare, so int atomicMax is exact.
// A plain-load pre-check filters atomics: agg is monotone non-decreasing, so
// if the (possibly stale) current value already >= rel, the atomic would be a
// no-op and can be skipped safely.
// ---------------------------------------------------------------------------
__global__ __launch_bounds__(256) void edge_kernel(
    const float* __restrict__ x,
    const int* __restrict__ src,
    const int* __restrict__ dst,
    float* __restrict__ agg) {
    long long t = (long long)blockIdx.x * blockDim.x + threadIdx.x;
    const long long total = (long long)N_EDGES * 16;   // 16 quads of 4 floats
    if (t >= total) return;
    int e = (int)(t >> 4);
    int q = (int)(t & 15);
    int s = src[e];
    int d = dst[e];
    const float4 xs = *(const float4*)(x + (long long)s * D + q * 4);
    const float4 xd = *(const float4*)(x + (long long)d * D + q * 4);
    float r0 = xs.x - xd.x;
    float r1 = xs.y - xd.y;
    float r2 = xs.z - xd.z;
    float r3 = xs.w - xd.w;
    float* ap = agg + (long long)d * D + q * 4;
    int* ai = (int*)ap;
    if (r0 > 0.0f && r0 > ap[0]) atomicMax(&ai[0], __float_as_int(r0));
    if (r1 > 0.0f && r1 > ap[1]) atomicMax(&ai[1], __float_as_int(r1));
    if (r2 > 0.0f && r2 > ap[2]) atomicMax(&ai[2], __float_as_int(r2));
    if (r3 > 0.0f && r3 > ap[3]) atomicMax(&ai[3], __float_as_int(r3));
}

// ---------------------------------------------------------------------------
// Node kernel: one wave per node.
//   h = concat([x_n, agg_n]) @ W + b ; LayerNorm ; ELU
// W (128x64 = 32 KB) staged in LDS once per block. Lane d owns output col d.
// Inputs broadcast across the wave via __shfl. LDS reads Wl[k*64+lane] are
// stride-1 across lanes -> 2 lanes/bank, conflict-free on CDNA.
// ---------------------------------------------------------------------------
__global__ __launch_bounds__(256) void node_kernel(
    const float* __restrict__ x,
    const float* __restrict__ agg,
    const float* __restrict__ W,
    const float* __restrict__ b,
    const float* __restrict__ gamma,
    const float* __restrict__ beta,
    float* __restrict__ out) {
    __shared__ float Wl[TWO_D * D];
    __shared__ float bl[D], gl[D], bt[D];

    for (int i = threadIdx.x; i < TWO_D * D; i += 256) Wl[i] = W[i];
    if (threadIdx.x < D) {
        bl[threadIdx.x] = b[threadIdx.x];
        gl[threadIdx.x] = gamma[threadIdx.x];
        bt[threadIdx.x] = beta[threadIdx.x];
    }
    __syncthreads();

    const int lane = threadIdx.x & 63;
    const int wave = threadIdx.x >> 6;

    for (int n = blockIdx.x * 4 + wave; n < N_NODES; n += gridDim.x * 4) {
        const float in0 = x[(long long)n * D + lane];
        const float in1 = agg[(long long)n * D + lane];

        float h = bl[lane];
#pragma unroll
        for (int k = 0; k < D; ++k)
            h += __shfl(in0, k, 64) * Wl[k * D + lane];
#pragma unroll
        for (int k = 0; k < D; ++k)
            h += __shfl(in1, k, 64) * Wl[(D + k) * D + lane];

        // LayerNorm across the 64 lanes
        float s = h;
#pragma unroll
        for (int off = 32; off; off >>= 1) s += __shfl_xor(s, off, 64);
        const float mu = s * (1.0f / 64.0f);
        const float dv = h - mu;
        float v = dv * dv;
#pragma unroll
        for (int off = 32; off; off >>= 1) v += __shfl_xor(v, off, 64);
        v *= (1.0f / 64.0f);

        float hn = dv * rsqrtf(v + LN_EPS) * gl[lane] + bt[lane];
        // ELU (alpha = 1)
        out[(long long)n * D + lane] = hn > 0.0f ? hn : expm1f(hn);
    }
}

extern "C" void kernel_launch(void* const* d_in, const int* in_sizes, int n_in,
                              void* d_out, int out_size, void* d_ws, size_t ws_size,
                              hipStream_t stream) {
    const float* features = (const float*)d_in[0];
    const int*   src      = (const int*)d_in[1];
    const int*   dst      = (const int*)d_in[2];
    const float* Ws       = (const float*)d_in[3];
    const float* bs       = (const float*)d_in[4];
    const float* gammas   = (const float*)d_in[5];
    const float* betas    = (const float*)d_in[6];
    float* out = (float*)d_out;

    float* agg = (float*)d_ws;                              // N*D f32 = 25.6 MB
    float* xA  = (float*)d_ws + (size_t)N_NODES * D;        // N*D f32 = 25.6 MB

    const size_t agg_bytes = sizeof(float) * (size_t)N_NODES * D;

    const long long e_threads = (long long)N_EDGES * 16;
    const int e_blocks = (int)((e_threads + 255) / 256);
    const int n_blocks = 4096;   // 4 waves/block, grid-stride over nodes

    const float* xcur = features;
    float* bufs[3] = { xA, out, out };   // layer3 node kernel is in-place safe

    for (int l = 0; l < 3; ++l) {
        hipMemsetAsync(agg, 0, agg_bytes, stream);
        edge_kernel<<<e_blocks, 256, 0, stream>>>(xcur, src, dst, agg);
        node_kernel<<<n_blocks, 256, 0, stream>>>(
            xcur, agg,
            Ws + (size_t)l * TWO_D * D,
            bs + (size_t)l * D,
            gammas + (size_t)l * D,
            betas + (size_t)l * D,
            bufs[l]);
        xcur = bufs[l];
    }
}

// Round 2
// 623.175 us; speedup vs baseline: 4.5513x; 4.5513x over previous
//
#include <hip/hip_runtime.h>
#include <math.h>

#define N_NODES 100000
#define N_EDGES 1600000
#define D 64
#define TWO_D 128
#define LN_EPS 1e-5f
#define SCAN_BS 256
#define SCAN_NB ((N_NODES + SCAN_BS - 1) / SCAN_BS)   // 391

// ---------------------------------------------------------------------------
// Counting-sort by dst -> CSR (row_ptr + sorted src list). Indices are the
// same for all 3 layers, so this runs once per kernel_launch.
// ---------------------------------------------------------------------------
__global__ __launch_bounds__(256) void hist_kernel(const int* __restrict__ dst,
                                                   int* __restrict__ cnt) {
    int e = blockIdx.x * 256 + threadIdx.x;
    if (e < N_EDGES) atomicAdd(&cnt[dst[e]], 1);
}

__global__ __launch_bounds__(SCAN_BS) void scan_part1(const int* __restrict__ cnt,
                                                      int* __restrict__ bsum) {
    __shared__ int lds[SCAN_BS];
    int i = blockIdx.x * SCAN_BS + threadIdx.x;
    lds[threadIdx.x] = (i < N_NODES) ? cnt[i] : 0;
    __syncthreads();
    for (int off = SCAN_BS / 2; off; off >>= 1) {
        if (threadIdx.x < off) lds[threadIdx.x] += lds[threadIdx.x + off];
        __syncthreads();
    }
    if (threadIdx.x == 0) bsum[blockIdx.x] = lds[0];
}

__global__ __launch_bounds__(512) void scan_part2(int* __restrict__ bsum) {
    __shared__ int lds[512];
    int v = (threadIdx.x < SCAN_NB) ? bsum[threadIdx.x] : 0;
    lds[threadIdx.x] = v;
    __syncthreads();
    for (int off = 1; off < 512; off <<= 1) {
        int t = (threadIdx.x >= off) ? lds[threadIdx.x - off] : 0;
        __syncthreads();
        lds[threadIdx.x] += t;
        __syncthreads();
    }
    if (threadIdx.x < SCAN_NB) bsum[threadIdx.x] = lds[threadIdx.x] - v;  // exclusive
}

__global__ __launch_bounds__(SCAN_BS) void scan_part3(const int* __restrict__ cnt,
                                                      const int* __restrict__ bsum,
                                                      int* __restrict__ row_ptr) {
    __shared__ int lds[SCAN_BS];
    int i = blockIdx.x * SCAN_BS + threadIdx.x;
    int v = (i < N_NODES) ? cnt[i] : 0;
    lds[threadIdx.x] = v;
    __syncthreads();
    for (int off = 1; off < SCAN_BS; off <<= 1) {
        int t = (threadIdx.x >= off) ? lds[threadIdx.x - off] : 0;
        __syncthreads();
        lds[threadIdx.x] += t;
        __syncthreads();
    }
    if (i < N_NODES) row_ptr[i] = bsum[blockIdx.x] + lds[threadIdx.x] - v;  // exclusive
    if (i == N_NODES - 1) row_ptr[N_NODES] = bsum[blockIdx.x] + lds[threadIdx.x];
}

__global__ __launch_bounds__(256) void scatter_kernel(const int* __restrict__ src,
                                                      const int* __restrict__ dst,
                                                      int* __restrict__ offs,
                                                      int* __restrict__ ssrc) {
    int e = blockIdx.x * 256 + threadIdx.x;
    if (e < N_EDGES) {
        int p = atomicAdd(&offs[dst[e]], 1);
        ssrc[p] = src[e];
    }
}

__device__ __forceinline__ float readlane_f(float v, int l) {
    return __int_as_float(__builtin_amdgcn_readlane(__float_as_int(v), l));
}

// ---------------------------------------------------------------------------
// Fused layer: per wave, 2 nodes. CSR gather-max of src rows (register agg,
// no atomics), then GEMV (W^T in LDS, padded 132 -> conflict-free b128 reads,
// readlane broadcasts), LayerNorm, ELU.
// max_j(x_src - x_dst) == max_j(x_src) - x_dst  -> subtract hoisted.
// ---------------------------------------------------------------------------
__global__ __launch_bounds__(256) void layer_kernel(
    const float* __restrict__ x,
    const int* __restrict__ row_ptr,
    const int* __restrict__ ssrc,
    const float* __restrict__ W,
    const float* __restrict__ b,
    const float* __restrict__ gamma,
    const float* __restrict__ beta,
    float* __restrict__ out)
{
    __shared__ float Wt[D][132];   // Wt[d][k] = W[k][d], padded to 132 floats
    for (int i = threadIdx.x; i < TWO_D * D; i += 256) {
        Wt[i & 63][i >> 6] = W[i];
    }
    __syncthreads();

    const int lane = threadIdx.x & 63;
    const int wave = threadIdx.x >> 6;
    const float bv = b[lane], gv = gamma[lane], btv = beta[lane];
    const float* wrow = &Wt[lane][0];
    const int nwaves = gridDim.x * 4;

    for (int p = blockIdx.x * 4 + wave; 2 * p < N_NODES; p += nwaves) {
        const int n0 = 2 * p, n1 = 2 * p + 1;   // N even -> both valid

        float xd0 = x[n0 * D + lane];
        float xd1 = x[n1 * D + lane];

        float agg0, agg1;
        {
            const int beg = row_ptr[n0], end = row_ptr[n0 + 1];
            float mx = -INFINITY;
            for (int j = beg; j < end; j += 64) {
                const int cnt = min(end - j, 64);
                const int idx = ssrc[j + min(lane, cnt - 1)];
                int t = 0;
                for (; t + 4 <= cnt; t += 4) {
                    int s0 = __builtin_amdgcn_readlane(idx, t);
                    int s1 = __builtin_amdgcn_readlane(idx, t + 1);
                    int s2 = __builtin_amdgcn_readlane(idx, t + 2);
                    int s3 = __builtin_amdgcn_readlane(idx, t + 3);
                    float v0 = x[s0 * D + lane];
                    float v1 = x[s1 * D + lane];
                    float v2 = x[s2 * D + lane];
                    float v3 = x[s3 * D + lane];
                    mx = fmaxf(mx, fmaxf(fmaxf(v0, v1), fmaxf(v2, v3)));
                }
                for (; t < cnt; ++t) {
                    int s = __builtin_amdgcn_readlane(idx, t);
                    mx = fmaxf(mx, x[s * D + lane]);
                }
            }
            agg0 = (end > beg) ? fmaxf(mx - xd0, 0.0f) : 0.0f;
        }
        {
            const int beg = row_ptr[n1], end = row_ptr[n1 + 1];
            float mx = -INFINITY;
            for (int j = beg; j < end; j += 64) {
                const int cnt = min(end - j, 64);
                const int idx = ssrc[j + min(lane, cnt - 1)];
                int t = 0;
                for (; t + 4 <= cnt; t += 4) {
                    int s0 = __builtin_amdgcn_readlane(idx, t);
                    int s1 = __builtin_amdgcn_readlane(idx, t + 1);
                    int s2 = __builtin_amdgcn_readlane(idx, t + 2);
                    int s3 = __builtin_amdgcn_readlane(idx, t + 3);
                    float v0 = x[s0 * D + lane];
                    float v1 = x[s1 * D + lane];
                    float v2 = x[s2 * D + lane];
                    float v3 = x[s3 * D + lane];
                    mx = fmaxf(mx, fmaxf(fmaxf(v0, v1), fmaxf(v2, v3)));
                }
                for (; t < cnt; ++t) {
                    int s = __builtin_amdgcn_readlane(idx, t);
                    mx = fmaxf(mx, x[s * D + lane]);
                }
            }
            agg1 = (end > beg) ? fmaxf(mx - xd1, 0.0f) : 0.0f;
        }

        // GEMV: h[d] = sum_k in[k]*W[k][d] + b[d]; in = concat(x_row, agg)
        float a0 = bv, a1 = 0.f, a2 = 0.f, a3 = 0.f;
        float b0 = bv, b1 = 0.f, b2 = 0.f, b3 = 0.f;
#pragma unroll
        for (int t = 0; t < 16; ++t) {
            const float4 wq = *(const float4*)(wrow + t * 4);
            a0 += readlane_f(xd0, 4 * t)     * wq.x;
            a1 += readlane_f(xd0, 4 * t + 1) * wq.y;
            a2 += readlane_f(xd0, 4 * t + 2) * wq.z;
            a3 += readlane_f(xd0, 4 * t + 3) * wq.w;
            b0 += readlane_f(xd1, 4 * t)     * wq.x;
            b1 += readlane_f(xd1, 4 * t + 1) * wq.y;
            b2 += readlane_f(xd1, 4 * t + 2) * wq.z;
            b3 += readlane_f(xd1, 4 * t + 3) * wq.w;
        }
#pragma unroll
        for (int t = 0; t < 16; ++t) {
            const float4 wq = *(const float4*)(wrow + 64 + t * 4);
            a0 += readlane_f(agg0, 4 * t)     * wq.x;
            a1 += readlane_f(agg0, 4 * t + 1) * wq.y;
            a2 += readlane_f(agg0, 4 * t + 2) * wq.z;
            a3 += readlane_f(agg0, 4 * t + 3) * wq.w;
            b0 += readlane_f(agg1, 4 * t)     * wq.x;
            b1 += readlane_f(agg1, 4 * t + 1) * wq.y;
            b2 += readlane_f(agg1, 4 * t + 2) * wq.z;
            b3 += readlane_f(agg1, 4 * t + 3) * wq.w;
        }
        float h0 = (a0 + a1) + (a2 + a3);
        float h1 = (b0 + b1) + (b2 + b3);

        // LayerNorm across 64 lanes + ELU, for both nodes
        float s0 = h0, s1 = h1;
#pragma unroll
        for (int off = 32; off; off >>= 1) {
            s0 += __shfl_xor(s0, off, 64);
            s1 += __shfl_xor(s1, off, 64);
        }
        const float mu0 = s0 * (1.0f / 64.0f);
        const float mu1 = s1 * (1.0f / 64.0f);
        const float dv0 = h0 - mu0, dv1 = h1 - mu1;
        float v0 = dv0 * dv0, v1 = dv1 * dv1;
#pragma unroll
        for (int off = 32; off; off >>= 1) {
            v0 += __shfl_xor(v0, off, 64);
            v1 += __shfl_xor(v1, off, 64);
        }
        v0 *= (1.0f / 64.0f);
        v1 *= (1.0f / 64.0f);

        float hn0 = dv0 * rsqrtf(v0 + LN_EPS) * gv + btv;
        float hn1 = dv1 * rsqrtf(v1 + LN_EPS) * gv + btv;
        out[n0 * D + lane] = hn0 > 0.0f ? hn0 : expm1f(hn0);
        out[n1 * D + lane] = hn1 > 0.0f ? hn1 : expm1f(hn1);
    }
}

static inline size_t alignup(size_t v) { return (v + 255) & ~(size_t)255; }

extern "C" void kernel_launch(void* const* d_in, const int* in_sizes, int n_in,
                              void* d_out, int out_size, void* d_ws, size_t ws_size,
                              hipStream_t stream) {
    const float* features = (const float*)d_in[0];
    const int*   src      = (const int*)d_in[1];
    const int*   dst      = (const int*)d_in[2];
    const float* Ws       = (const float*)d_in[3];
    const float* bs       = (const float*)d_in[4];
    const float* gammas   = (const float*)d_in[5];
    const float* betas    = (const float*)d_in[6];
    float* out = (float*)d_out;

    char* ws = (char*)d_ws;
    size_t off = 0;
    int* row_ptr = (int*)(ws + off); off = alignup(off + sizeof(int) * (N_NODES + 1));
    int* offs    = (int*)(ws + off); off = alignup(off + sizeof(int) * N_NODES);
    int* cnt     = (int*)(ws + off); off = alignup(off + sizeof(int) * N_NODES);
    int* bsum    = (int*)(ws + off); off = alignup(off + sizeof(int) * 512);
    int* ssrc    = (int*)(ws + off); off = alignup(off + sizeof(int) * N_EDGES);
    float* xA    = (float*)(ws + off); off = alignup(off + sizeof(float) * (size_t)N_NODES * D);
    float* xB    = (float*)(ws + off);

    // --- build CSR (once; indices identical across layers) ---
    hipMemsetAsync(cnt, 0, sizeof(int) * N_NODES, stream);
    hist_kernel<<<(N_EDGES + 255) / 256, 256, 0, stream>>>(dst, cnt);
    scan_part1<<<SCAN_NB, SCAN_BS, 0, stream>>>(cnt, bsum);
    scan_part2<<<1, 512, 0, stream>>>(bsum);
    scan_part3<<<SCAN_NB, SCAN_BS, 0, stream>>>(cnt, bsum, row_ptr);
    hipMemcpyAsync(offs, row_ptr, sizeof(int) * N_NODES, hipMemcpyDeviceToDevice, stream);
    scatter_kernel<<<(N_EDGES + 255) / 256, 256, 0, stream>>>(src, dst, offs, ssrc);

    // --- 3 fused layers: features -> xA -> xB -> out ---
    const float* xin = features;
    float* bufs[3] = { xA, xB, out };
    for (int l = 0; l < 3; ++l) {
        layer_kernel<<<2048, 256, 0, stream>>>(
            xin, row_ptr, ssrc,
            Ws + (size_t)l * TWO_D * D,
            bs + (size_t)l * D,
            gammas + (size_t)l * D,
            betas + (size_t)l * D,
            bufs[l]);
        xin = bufs[l];
    }
}

// Round 3
// 358.743 us; speedup vs baseline: 7.9062x; 1.7371x over previous
//
#include <hip/hip_runtime.h>
#include <hip/hip_bf16.h>
#include <math.h>

#define N_NODES 100000
#define N_EDGES 1600000
#define D 64
#define TWO_D 128
#define LN_EPS 1e-5f
#define SCAN_BS 256
#define SCAN_NB ((N_NODES + SCAN_BS - 1) / SCAN_BS)   // 391

typedef __attribute__((ext_vector_type(4))) float f32x4;
typedef __attribute__((ext_vector_type(8))) short bf16x8;

__device__ __forceinline__ float b2f(unsigned short u) {
    return __uint_as_float(((unsigned)u) << 16);
}
__device__ __forceinline__ unsigned short f2b(float f) {
    __hip_bfloat16 h = __float2bfloat16(f);   // RNE
    return __builtin_bit_cast(unsigned short, h);
}

// ---------------------------------------------------------------------------
// CSR build: counting sort by dst (once per call; indices layer-invariant)
// ---------------------------------------------------------------------------
__global__ __launch_bounds__(256) void hist_kernel(const int* __restrict__ dst,
                                                   int* __restrict__ cnt) {
    int e = blockIdx.x * 256 + threadIdx.x;
    if (e < N_EDGES) atomicAdd(&cnt[dst[e]], 1);
}

__global__ __launch_bounds__(SCAN_BS) void scan_part1(const int* __restrict__ cnt,
                                                      int* __restrict__ bsum) {
    __shared__ int lds[SCAN_BS];
    int i = blockIdx.x * SCAN_BS + threadIdx.x;
    lds[threadIdx.x] = (i < N_NODES) ? cnt[i] : 0;
    __syncthreads();
    for (int off = SCAN_BS / 2; off; off >>= 1) {
        if (threadIdx.x < off) lds[threadIdx.x] += lds[threadIdx.x + off];
        __syncthreads();
    }
    if (threadIdx.x == 0) bsum[blockIdx.x] = lds[0];
}

__global__ __launch_bounds__(512) void scan_part2(int* __restrict__ bsum) {
    __shared__ int lds[512];
    int v = (threadIdx.x < SCAN_NB) ? bsum[threadIdx.x] : 0;
    lds[threadIdx.x] = v;
    __syncthreads();
    for (int off = 1; off < 512; off <<= 1) {
        int t = (threadIdx.x >= off) ? lds[threadIdx.x - off] : 0;
        __syncthreads();
        lds[threadIdx.x] += t;
        __syncthreads();
    }
    if (threadIdx.x < SCAN_NB) bsum[threadIdx.x] = lds[threadIdx.x] - v;  // exclusive
}

__global__ __launch_bounds__(SCAN_BS) void scan_part3(const int* __restrict__ cnt,
                                                      const int* __restrict__ bsum,
                                                      int* __restrict__ row_ptr) {
    __shared__ int lds[SCAN_BS];
    int i = blockIdx.x * SCAN_BS + threadIdx.x;
    int v = (i < N_NODES) ? cnt[i] : 0;
    lds[threadIdx.x] = v;
    __syncthreads();
    for (int off = 1; off < SCAN_BS; off <<= 1) {
        int t = (threadIdx.x >= off) ? lds[threadIdx.x - off] : 0;
        __syncthreads();
        lds[threadIdx.x] += t;
        __syncthreads();
    }
    if (i < N_NODES) row_ptr[i] = bsum[blockIdx.x] + lds[threadIdx.x] - v;  // exclusive
    if (i == N_NODES - 1) row_ptr[N_NODES] = bsum[blockIdx.x] + lds[threadIdx.x];
}

__global__ __launch_bounds__(256) void scatter_kernel(const int* __restrict__ src,
                                                      const int* __restrict__ dst,
                                                      int* __restrict__ offs,
                                                      int* __restrict__ ssrc) {
    int e = blockIdx.x * 256 + threadIdx.x;
    if (e < N_EDGES) {
        int p = atomicAdd(&offs[dst[e]], 1);
        ssrc[p] = src[e];
    }
}

// ---------------------------------------------------------------------------
// Converters
// ---------------------------------------------------------------------------
__global__ __launch_bounds__(256) void cvt_x_kernel(const float* __restrict__ xf,
                                                    ushort* __restrict__ xb) {
    int i = blockIdx.x * 256 + threadIdx.x;            // one float4 each
    if (i < N_NODES * D / 4) {
        float4 v = ((const float4*)xf)[i];
        ushort4 o;
        o.x = f2b(v.x); o.y = f2b(v.y); o.z = f2b(v.z); o.w = f2b(v.w);
        ((ushort4*)xb)[i] = o;
    }
}

// Wperm[lay][s][c][lane][j] = bf16(W[lay][32s + 8*(lane>>4) + j][16c + (lane&15)])
// -> B-fragments for mfma_f32_16x16x32_bf16 load as one dwordx4 per lane.
__global__ __launch_bounds__(256) void cvt_w_kernel(const float* __restrict__ Ws,
                                                    ushort* __restrict__ Wperm) {
    int i = blockIdx.x * 256 + threadIdx.x;
    if (i >= 3 * 4 * 4 * 64 * 8) return;
    int j    = i & 7;
    int lane = (i >> 3) & 63;
    int c    = (i >> 9) & 3;
    int s    = (i >> 11) & 3;
    int lay  = i >> 13;
    int k = 32 * s + 8 * (lane >> 4) + j;
    int d = 16 * c + (lane & 15);
    Wperm[i] = f2b(Ws[((size_t)lay * TWO_D + k) * D + d]);
}

// ---------------------------------------------------------------------------
// Gather-max kernel: quarter-wave (16 lanes) per node, lane owns 4 features
// (ushort4 = 8 B; 16 lanes = one 128 B bf16 row). Edge indices batch-loaded
// and broadcast within the quarter-wave via __shfl (ds_bpermute). Register
// max, no atomics. agg = max(max_j x_src - x_dst, 0), stored bf16.
// ---------------------------------------------------------------------------
__global__ __launch_bounds__(256) void gather_kernel(
    const ushort* __restrict__ xb,
    const int* __restrict__ row_ptr,
    const int* __restrict__ ssrc,
    ushort* __restrict__ agg)
{
    const int qw = blockIdx.x * 16 + (threadIdx.x >> 4);   // node id
    if (qw >= N_NODES) return;
    const int fl = threadIdx.x & 15;
    const int base = threadIdx.x & 48;                     // quarter-wave lane base
    const ushort4* __restrict__ x4 = (const ushort4*)xb;

    const ushort4 xs = x4[qw * 16 + fl];
    const float xd0 = b2f(xs.x), xd1 = b2f(xs.y), xd2 = b2f(xs.z), xd3 = b2f(xs.w);

    const int beg = row_ptr[qw], end = row_ptr[qw + 1];
    float m0 = -INFINITY, m1 = -INFINITY, m2 = -INFINITY, m3 = -INFINITY;

    for (int j = beg; j < end; j += 16) {
        const int cnt = min(end - j, 16);
        const int idx = ssrc[j + min(fl, cnt - 1)];
        int t = 0;
        for (; t + 4 <= cnt; t += 4) {
            int s0 = __shfl(idx, base + t,     64);
            int s1 = __shfl(idx, base + t + 1, 64);
            int s2 = __shfl(idx, base + t + 2, 64);
            int s3 = __shfl(idx, base + t + 3, 64);
            ushort4 a = x4[s0 * 16 + fl];
            ushort4 b = x4[s1 * 16 + fl];
            ushort4 c = x4[s2 * 16 + fl];
            ushort4 d = x4[s3 * 16 + fl];
            m0 = fmaxf(fmaxf(m0, b2f(a.x)), fmaxf(fmaxf(b2f(b.x), b2f(c.x)), b2f(d.x)));
            m1 = fmaxf(fmaxf(m1, b2f(a.y)), fmaxf(fmaxf(b2f(b.y), b2f(c.y)), b2f(d.y)));
            m2 = fmaxf(fmaxf(m2, b2f(a.z)), fmaxf(fmaxf(b2f(b.z), b2f(c.z)), b2f(d.z)));
            m3 = fmaxf(fmaxf(m3, b2f(a.w)), fmaxf(fmaxf(b2f(b.w), b2f(c.w)), b2f(d.w)));
        }
        for (; t < cnt; ++t) {
            int s0 = __shfl(idx, base + t, 64);
            ushort4 a = x4[s0 * 16 + fl];
            m0 = fmaxf(m0, b2f(a.x));
            m1 = fmaxf(m1, b2f(a.y));
            m2 = fmaxf(m2, b2f(a.z));
            m3 = fmaxf(m3, b2f(a.w));
        }
    }

    float r0 = 0.f, r1 = 0.f, r2 = 0.f, r3 = 0.f;
    if (end > beg) {
        r0 = fmaxf(m0 - xd0, 0.f);
        r1 = fmaxf(m1 - xd1, 0.f);
        r2 = fmaxf(m2 - xd2, 0.f);
        r3 = fmaxf(m3 - xd3, 0.f);
    }
    ushort4 o;
    o.x = f2b(r0); o.y = f2b(r1); o.z = f2b(r2); o.w = f2b(r3);
    ((ushort4*)agg)[qw * 16 + fl] = o;
}

// ---------------------------------------------------------------------------
// MFMA GEMM + bias + LayerNorm + ELU. Wave per 16 nodes, full 64 output cols.
// h[16x64] = [x | agg][16x128] @ W[128x64]; 4 col-tiles x 4 K-steps = 16 MFMA.
// A-frag: lane holds rows n0+(lane&15), k = 8*(lane>>4)+j (16 B contiguous,
// wave covers a contiguous 2 KB). B-frags preloaded from Wperm.
// C-layout: col = 16c + (lane&15), row = 4*(lane>>4) + j -> LN row-reduce is
// a 16-lane shfl_xor {1,2,4,8}.
// ---------------------------------------------------------------------------
__global__ __launch_bounds__(256) void gemm_kernel(
    const ushort* __restrict__ xb,
    const ushort* __restrict__ agg,
    const ushort* __restrict__ Wperm,   // this layer's [4][4][64][8]
    const float* __restrict__ bias,
    const float* __restrict__ gamma,
    const float* __restrict__ beta,
    ushort* __restrict__ out_b,         // bf16 out (layers 0,1) or nullptr
    float*  __restrict__ out_f)         // f32 out (layer 2) or nullptr
{
    const int wid = (blockIdx.x * 256 + threadIdx.x) >> 6;
    if (wid >= N_NODES / 16) return;
    const int lane = threadIdx.x & 63;
    const int n0 = wid * 16;
    const int row = lane & 15;
    const int kb  = lane >> 4;

    const bf16x8* __restrict__ wp = (const bf16x8*)Wperm;
    bf16x8 wf[4][4];
#pragma unroll
    for (int s = 0; s < 4; ++s)
#pragma unroll
        for (int c = 0; c < 4; ++c)
            wf[s][c] = wp[(s * 4 + c) * 64 + lane];

    const bf16x8* __restrict__ xv = (const bf16x8*)xb;
    const bf16x8* __restrict__ av = (const bf16x8*)agg;
    bf16x8 a0 = xv[(n0 + row) * 8 + kb];
    bf16x8 a1 = xv[(n0 + row) * 8 + 4 + kb];
    bf16x8 a2 = av[(n0 + row) * 8 + kb];
    bf16x8 a3 = av[(n0 + row) * 8 + 4 + kb];

    f32x4 acc[4];
#pragma unroll
    for (int c = 0; c < 4; ++c) acc[c] = (f32x4){0.f, 0.f, 0.f, 0.f};
#pragma unroll
    for (int c = 0; c < 4; ++c) {
        acc[c] = __builtin_amdgcn_mfma_f32_16x16x32_bf16(a0, wf[0][c], acc[c], 0, 0, 0);
        acc[c] = __builtin_amdgcn_mfma_f32_16x16x32_bf16(a1, wf[1][c], acc[c], 0, 0, 0);
        acc[c] = __builtin_amdgcn_mfma_f32_16x16x32_bf16(a2, wf[2][c], acc[c], 0, 0, 0);
        acc[c] = __builtin_amdgcn_mfma_f32_16x16x32_bf16(a3, wf[3][c], acc[c], 0, 0, 0);
    }

    float bv[4], gv[4], btv[4];
#pragma unroll
    for (int c = 0; c < 4; ++c) {
        const int col = 16 * c + row;
        bv[c] = bias[col]; gv[c] = gamma[col]; btv[c] = beta[col];
    }

#pragma unroll
    for (int j = 0; j < 4; ++j) {
        float h0 = acc[0][j] + bv[0];
        float h1 = acc[1][j] + bv[1];
        float h2 = acc[2][j] + bv[2];
        float h3 = acc[3][j] + bv[3];
        float ps = (h0 + h1) + (h2 + h3);
        ps += __shfl_xor(ps, 1, 64);
        ps += __shfl_xor(ps, 2, 64);
        ps += __shfl_xor(ps, 4, 64);
        ps += __shfl_xor(ps, 8, 64);
        const float mu = ps * (1.0f / 64.0f);
        const float d0 = h0 - mu, d1 = h1 - mu, d2 = h2 - mu, d3 = h3 - mu;
        float vs = (d0 * d0 + d1 * d1) + (d2 * d2 + d3 * d3);
        vs += __shfl_xor(vs, 1, 64);
        vs += __shfl_xor(vs, 2, 64);
        vs += __shfl_xor(vs, 4, 64);
        vs += __shfl_xor(vs, 8, 64);
        const float rstd = rsqrtf(vs * (1.0f / 64.0f) + LN_EPS);

        const int node = n0 + 4 * kb + j;
        const float dd[4] = {d0, d1, d2, d3};
#pragma unroll
        for (int c = 0; c < 4; ++c) {
            float o = dd[c] * rstd * gv[c] + btv[c];
            o = o > 0.f ? o : expm1f(o);
            if (out_f) out_f[node * D + 16 * c + row] = o;
            else       out_b[node * D + 16 * c + row] = f2b(o);
        }
    }
}

static inline size_t alignup(size_t v) { return (v + 255) & ~(size_t)255; }

extern "C" void kernel_launch(void* const* d_in, const int* in_sizes, int n_in,
                              void* d_out, int out_size, void* d_ws, size_t ws_size,
                              hipStream_t stream) {
    const float* features = (const float*)d_in[0];
    const int*   src      = (const int*)d_in[1];
    const int*   dst      = (const int*)d_in[2];
    const float* Ws       = (const float*)d_in[3];
    const float* bs       = (const float*)d_in[4];
    const float* gammas   = (const float*)d_in[5];
    const float* betas    = (const float*)d_in[6];
    float* out = (float*)d_out;

    char* ws = (char*)d_ws;
    size_t off = 0;
    int* row_ptr = (int*)(ws + off); off = alignup(off + sizeof(int) * (N_NODES + 1));
    int* offs    = (int*)(ws + off); off = alignup(off + sizeof(int) * N_NODES);
    int* cnt     = (int*)(ws + off); off = alignup(off + sizeof(int) * N_NODES);
    int* bsum    = (int*)(ws + off); off = alignup(off + sizeof(int) * 512);
    int* ssrc    = (int*)(ws + off); off = alignup(off + sizeof(int) * N_EDGES);
    ushort* xbA  = (ushort*)(ws + off); off = alignup(off + sizeof(ushort) * (size_t)N_NODES * D);
    ushort* xbB  = (ushort*)(ws + off); off = alignup(off + sizeof(ushort) * (size_t)N_NODES * D);
    ushort* aggb = (ushort*)(ws + off); off = alignup(off + sizeof(ushort) * (size_t)N_NODES * D);
    ushort* Wperm= (ushort*)(ws + off); off = alignup(off + sizeof(ushort) * 3 * TWO_D * D);

    // --- build CSR (once) ---
    hipMemsetAsync(cnt, 0, sizeof(int) * N_NODES, stream);
    hist_kernel<<<(N_EDGES + 255) / 256, 256, 0, stream>>>(dst, cnt);
    scan_part1<<<SCAN_NB, SCAN_BS, 0, stream>>>(cnt, bsum);
    scan_part2<<<1, 512, 0, stream>>>(bsum);
    scan_part3<<<SCAN_NB, SCAN_BS, 0, stream>>>(cnt, bsum, row_ptr);
    hipMemcpyAsync(offs, row_ptr, sizeof(int) * N_NODES, hipMemcpyDeviceToDevice, stream);
    scatter_kernel<<<(N_EDGES + 255) / 256, 256, 0, stream>>>(src, dst, offs, ssrc);

    // --- converters ---
    cvt_x_kernel<<<(N_NODES * D / 4 + 255) / 256, 256, 0, stream>>>(features, xbA);
    cvt_w_kernel<<<(3 * 4 * 4 * 64 * 8 + 255) / 256, 256, 0, stream>>>(Ws, Wperm);

    // --- 3 layers ---
    const int g_blocks = N_NODES / 16;                 // 6250, quarter-wave/node
    const int m_blocks = (N_NODES / 16 + 3) / 4;       // 1563, wave/16-nodes

    ushort* xin = xbA;
    ushort* xnb[3] = { xbB, xbA, nullptr };
    for (int l = 0; l < 3; ++l) {
        gather_kernel<<<g_blocks, 256, 0, stream>>>(xin, row_ptr, ssrc, aggb);
        gemm_kernel<<<m_blocks, 256, 0, stream>>>(
            xin, aggb,
            Wperm + (size_t)l * 16 * 64 * 8,
            bs + (size_t)l * D,
            gammas + (size_t)l * D,
            betas + (size_t)l * D,
            xnb[l],
            (l == 2) ? out : nullptr);
        xin = xnb[l];
    }
}

// Round 4
// 216.170 us; speedup vs baseline: 13.1207x; 1.6595x over previous
//
#include <hip/hip_runtime.h>
#include <hip/hip_bf16.h>
#include <math.h>

#define N_NODES 100000
#define N_EDGES 1600000
#define D 64
#define TWO_D 128
#define LN_EPS 1e-5f

#define BSHIFT 7                                   // 128 nodes per bucket
#define NBUCK ((N_NODES + 127) >> BSHIFT)          // 782
#define EPB 8192                                   // edges per block (hist/scatter)
#define NEB ((N_EDGES + EPB - 1) / EPB)            // 196
#define STAGE_CAP 4096

typedef __attribute__((ext_vector_type(4))) float f32x4;
typedef __attribute__((ext_vector_type(8))) short bf16x8;

__device__ __forceinline__ float b2f(unsigned short u) {
    return __uint_as_float(((unsigned)u) << 16);
}
__device__ __forceinline__ unsigned short f2b(float f) {
    __hip_bfloat16 h = __float2bfloat16(f);   // RNE
    return __builtin_bit_cast(unsigned short, h);
}

// ---------------------------------------------------------------------------
// CSR build, two-level counting sort (once per call; indices layer-invariant)
// Level 1: 782 buckets of 128 nodes. Level 2: per-bucket LDS counting sort.
// ---------------------------------------------------------------------------
__global__ __launch_bounds__(256) void bhist_kernel(const int* __restrict__ dst,
                                                    int* __restrict__ bcnt_g) {
    __shared__ int h[NBUCK];
    for (int i = threadIdx.x; i < NBUCK; i += 256) h[i] = 0;
    __syncthreads();
    const int e0 = blockIdx.x * EPB;
    const int e1 = min(e0 + EPB, N_EDGES);
    for (int e = e0 + threadIdx.x; e < e1; e += 256)
        atomicAdd(&h[dst[e] >> BSHIFT], 1);
    __syncthreads();
    for (int i = threadIdx.x; i < NBUCK; i += 256)
        if (h[i]) atomicAdd(&bcnt_g[i], h[i]);
}

__global__ __launch_bounds__(1024) void bscan_kernel(const int* __restrict__ bcnt_g,
                                                     int* __restrict__ bbase,
                                                     int* __restrict__ bcur) {
    __shared__ int lds[1024];
    int v = (threadIdx.x < NBUCK) ? bcnt_g[threadIdx.x] : 0;
    lds[threadIdx.x] = v;
    __syncthreads();
    for (int off = 1; off < 1024; off <<= 1) {
        int t = (threadIdx.x >= off) ? lds[threadIdx.x - off] : 0;
        __syncthreads();
        lds[threadIdx.x] += t;
        __syncthreads();
    }
    if (threadIdx.x < NBUCK) {
        int ex = lds[threadIdx.x] - v;     // exclusive
        bbase[threadIdx.x] = ex;
        bcur[threadIdx.x] = ex;
    }
    if (threadIdx.x == 0) bbase[NBUCK] = N_EDGES;
}

// Scatter (src,dst) pairs into per-bucket contiguous regions. Per-block LDS
// histogram -> one global atomicAdd per (block,bucket) -> per-edge LDS rank.
// Writes per bucket per block are ~10 consecutive pairs -> L2-coalesced.
__global__ __launch_bounds__(256) void bscat_kernel(const int* __restrict__ src,
                                                    const int* __restrict__ dst,
                                                    int* __restrict__ bcur,
                                                    int2* __restrict__ ebuf) {
    __shared__ int h[NBUCK];
    __shared__ int base[NBUCK];
    for (int i = threadIdx.x; i < NBUCK; i += 256) h[i] = 0;
    __syncthreads();
    const int e0 = blockIdx.x * EPB;
    const int e1 = min(e0 + EPB, N_EDGES);
    for (int e = e0 + threadIdx.x; e < e1; e += 256)
        atomicAdd(&h[dst[e] >> BSHIFT], 1);
    __syncthreads();
    for (int i = threadIdx.x; i < NBUCK; i += 256) {
        int c = h[i];
        if (c) base[i] = atomicAdd(&bcur[i], c);
        h[i] = 0;
    }
    __syncthreads();
    for (int e = e0 + threadIdx.x; e < e1; e += 256) {
        int d = dst[e];
        int b = d >> BSHIFT;
        int r = atomicAdd(&h[b], 1);
        ebuf[base[b] + r] = make_int2(src[e], d);
    }
}

// One block per bucket: LDS counting sort by node-within-bucket; emits
// row_ptr for its 128 nodes (global hist/scan eliminated) and streams ssrc
// out coalesced via an LDS stage.
__global__ __launch_bounds__(256) void bbuild_kernel(const int2* __restrict__ ebuf,
                                                     const int* __restrict__ bbase,
                                                     int* __restrict__ row_ptr,
                                                     int* __restrict__ ssrc) {
    __shared__ int cnt[128];
    __shared__ int excl[128];
    __shared__ int stage[STAGE_CAP];
    const int b = blockIdx.x;
    const int nb0 = b << BSHIFT;
    const int bb = bbase[b], be = bbase[b + 1];
    const int bcnt = be - bb;

    if (threadIdx.x < 128) cnt[threadIdx.x] = 0;
    __syncthreads();
    for (int i = threadIdx.x; i < bcnt; i += 256)
        atomicAdd(&cnt[ebuf[bb + i].y - nb0], 1);
    __syncthreads();

    // exclusive scan of cnt -> excl (Hillis-Steele over 128)
    int v = (threadIdx.x < 128) ? cnt[threadIdx.x] : 0;
    if (threadIdx.x < 128) excl[threadIdx.x] = v;
    __syncthreads();
    for (int off = 1; off < 128; off <<= 1) {
        int t = 0;
        if (threadIdx.x < 128 && threadIdx.x >= off) t = excl[threadIdx.x - off];
        __syncthreads();
        if (threadIdx.x < 128) excl[threadIdx.x] += t;
        __syncthreads();
    }
    if (threadIdx.x < 128) {
        excl[threadIdx.x] -= v;            // inclusive -> exclusive
        int node = nb0 + threadIdx.x;
        if (node < N_NODES) row_ptr[node] = bb + excl[threadIdx.x];
        cnt[threadIdx.x] = 0;
    }
    if (b == 0 && threadIdx.x == 0) row_ptr[N_NODES] = N_EDGES;
    __syncthreads();

    if (bcnt <= STAGE_CAP) {
        for (int i = threadIdx.x; i < bcnt; i += 256) {
            int2 e = ebuf[bb + i];
            int dl = e.y - nb0;
            int r = atomicAdd(&cnt[dl], 1);
            stage[excl[dl] + r] = e.x;
        }
        __syncthreads();
        for (int i = threadIdx.x; i < bcnt; i += 256)
            ssrc[bb + i] = stage[i];
    } else {   // fallback (degree skew) — correct, uncoalesced
        for (int i = threadIdx.x; i < bcnt; i += 256) {
            int2 e = ebuf[bb + i];
            int dl = e.y - nb0;
            int r = atomicAdd(&cnt[dl], 1);
            ssrc[bb + excl[dl] + r] = e.x;
        }
    }
}

// ---------------------------------------------------------------------------
// Converters
// ---------------------------------------------------------------------------
__global__ __launch_bounds__(256) void cvt_x_kernel(const float* __restrict__ xf,
                                                    ushort* __restrict__ xb) {
    int i = blockIdx.x * 256 + threadIdx.x;            // one float4 each
    if (i < N_NODES * D / 4) {
        float4 v = ((const float4*)xf)[i];
        ushort4 o;
        o.x = f2b(v.x); o.y = f2b(v.y); o.z = f2b(v.z); o.w = f2b(v.w);
        ((ushort4*)xb)[i] = o;
    }
}

// Wperm[lay][s][c][lane][j] = bf16(W[lay][32s + 8*(lane>>4) + j][16c + (lane&15)])
__global__ __launch_bounds__(256) void cvt_w_kernel(const float* __restrict__ Ws,
                                                    ushort* __restrict__ Wperm) {
    int i = blockIdx.x * 256 + threadIdx.x;
    if (i >= 3 * 4 * 4 * 64 * 8) return;
    int j    = i & 7;
    int lane = (i >> 3) & 63;
    int c    = (i >> 9) & 3;
    int s    = (i >> 11) & 3;
    int lay  = i >> 13;
    int k = 32 * s + 8 * (lane >> 4) + j;
    int d = 16 * c + (lane & 15);
    Wperm[i] = f2b(Ws[((size_t)lay * TWO_D + k) * D + d]);
}

// ---------------------------------------------------------------------------
// Gather-max kernel: quarter-wave (16 lanes) per node; register max, no
// atomics. agg = max(max_j x_src - x_dst, 0), stored bf16.
// ---------------------------------------------------------------------------
__global__ __launch_bounds__(256) void gather_kernel(
    const ushort* __restrict__ xb,
    const int* __restrict__ row_ptr,
    const int* __restrict__ ssrc,
    ushort* __restrict__ agg)
{
    const int qw = blockIdx.x * 16 + (threadIdx.x >> 4);   // node id
    if (qw >= N_NODES) return;
    const int fl = threadIdx.x & 15;
    const int base = threadIdx.x & 48;                     // quarter-wave lane base
    const ushort4* __restrict__ x4 = (const ushort4*)xb;

    const ushort4 xs = x4[qw * 16 + fl];
    const float xd0 = b2f(xs.x), xd1 = b2f(xs.y), xd2 = b2f(xs.z), xd3 = b2f(xs.w);

    const int beg = row_ptr[qw], end = row_ptr[qw + 1];
    float m0 = -INFINITY, m1 = -INFINITY, m2 = -INFINITY, m3 = -INFINITY;

    for (int j = beg; j < end; j += 16) {
        const int cnt = min(end - j, 16);
        const int idx = ssrc[j + min(fl, cnt - 1)];
        int t = 0;
        for (; t + 4 <= cnt; t += 4) {
            int s0 = __shfl(idx, base + t,     64);
            int s1 = __shfl(idx, base + t + 1, 64);
            int s2 = __shfl(idx, base + t + 2, 64);
            int s3 = __shfl(idx, base + t + 3, 64);
            ushort4 a = x4[s0 * 16 + fl];
            ushort4 b = x4[s1 * 16 + fl];
            ushort4 c = x4[s2 * 16 + fl];
            ushort4 d = x4[s3 * 16 + fl];
            m0 = fmaxf(fmaxf(m0, b2f(a.x)), fmaxf(fmaxf(b2f(b.x), b2f(c.x)), b2f(d.x)));
            m1 = fmaxf(fmaxf(m1, b2f(a.y)), fmaxf(fmaxf(b2f(b.y), b2f(c.y)), b2f(d.y)));
            m2 = fmaxf(fmaxf(m2, b2f(a.z)), fmaxf(fmaxf(b2f(b.z), b2f(c.z)), b2f(d.z)));
            m3 = fmaxf(fmaxf(m3, b2f(a.w)), fmaxf(fmaxf(b2f(b.w), b2f(c.w)), b2f(d.w)));
        }
        for (; t < cnt; ++t) {
            int s0 = __shfl(idx, base + t, 64);
            ushort4 a = x4[s0 * 16 + fl];
            m0 = fmaxf(m0, b2f(a.x));
            m1 = fmaxf(m1, b2f(a.y));
            m2 = fmaxf(m2, b2f(a.z));
            m3 = fmaxf(m3, b2f(a.w));
        }
    }

    float r0 = 0.f, r1 = 0.f, r2 = 0.f, r3 = 0.f;
    if (end > beg) {
        r0 = fmaxf(m0 - xd0, 0.f);
        r1 = fmaxf(m1 - xd1, 0.f);
        r2 = fmaxf(m2 - xd2, 0.f);
        r3 = fmaxf(m3 - xd3, 0.f);
    }
    ushort4 o;
    o.x = f2b(r0); o.y = f2b(r1); o.z = f2b(r2); o.w = f2b(r3);
    ((ushort4*)agg)[qw * 16 + fl] = o;
}

// ---------------------------------------------------------------------------
// MFMA GEMM + bias + LayerNorm + ELU. Wave per 16 nodes, 16 MFMA.
// C-layout: col = 16c + (lane&15), row = 4*(lane>>4) + j.
// ---------------------------------------------------------------------------
__global__ __launch_bounds__(256) void gemm_kernel(
    const ushort* __restrict__ xb,
    const ushort* __restrict__ agg,
    const ushort* __restrict__ Wperm,   // this layer's [4][4][64][8]
    const float* __restrict__ bias,
    const float* __restrict__ gamma,
    const float* __restrict__ beta,
    ushort* __restrict__ out_b,         // bf16 out (layers 0,1) or nullptr
    float*  __restrict__ out_f)         // f32 out (layer 2) or nullptr
{
    const int wid = (blockIdx.x * 256 + threadIdx.x) >> 6;
    if (wid >= N_NODES / 16) return;
    const int lane = threadIdx.x & 63;
    const int n0 = wid * 16;
    const int row = lane & 15;
    const int kb  = lane >> 4;

    const bf16x8* __restrict__ wp = (const bf16x8*)Wperm;
    bf16x8 wf[4][4];
#pragma unroll
    for (int s = 0; s < 4; ++s)
#pragma unroll
        for (int c = 0; c < 4; ++c)
            wf[s][c] = wp[(s * 4 + c) * 64 + lane];

    const bf16x8* __restrict__ xv = (const bf16x8*)xb;
    const bf16x8* __restrict__ av = (const bf16x8*)agg;
    bf16x8 a0 = xv[(n0 + row) * 8 + kb];
    bf16x8 a1 = xv[(n0 + row) * 8 + 4 + kb];
    bf16x8 a2 = av[(n0 + row) * 8 + kb];
    bf16x8 a3 = av[(n0 + row) * 8 + 4 + kb];

    f32x4 acc[4];
#pragma unroll
    for (int c = 0; c < 4; ++c) acc[c] = (f32x4){0.f, 0.f, 0.f, 0.f};
#pragma unroll
    for (int c = 0; c < 4; ++c) {
        acc[c] = __builtin_amdgcn_mfma_f32_16x16x32_bf16(a0, wf[0][c], acc[c], 0, 0, 0);
        acc[c] = __builtin_amdgcn_mfma_f32_16x16x32_bf16(a1, wf[1][c], acc[c], 0, 0, 0);
        acc[c] = __builtin_amdgcn_mfma_f32_16x16x32_bf16(a2, wf[2][c], acc[c], 0, 0, 0);
        acc[c] = __builtin_amdgcn_mfma_f32_16x16x32_bf16(a3, wf[3][c], acc[c], 0, 0, 0);
    }

    float bv[4], gv[4], btv[4];
#pragma unroll
    for (int c = 0; c < 4; ++c) {
        const int col = 16 * c + row;
        bv[c] = bias[col]; gv[c] = gamma[col]; btv[c] = beta[col];
    }

#pragma unroll
    for (int j = 0; j < 4; ++j) {
        float h0 = acc[0][j] + bv[0];
        float h1 = acc[1][j] + bv[1];
        float h2 = acc[2][j] + bv[2];
        float h3 = acc[3][j] + bv[3];
        float ps = (h0 + h1) + (h2 + h3);
        ps += __shfl_xor(ps, 1, 64);
        ps += __shfl_xor(ps, 2, 64);
        ps += __shfl_xor(ps, 4, 64);
        ps += __shfl_xor(ps, 8, 64);
        const float mu = ps * (1.0f / 64.0f);
        const float d0 = h0 - mu, d1 = h1 - mu, d2 = h2 - mu, d3 = h3 - mu;
        float vs = (d0 * d0 + d1 * d1) + (d2 * d2 + d3 * d3);
        vs += __shfl_xor(vs, 1, 64);
        vs += __shfl_xor(vs, 2, 64);
        vs += __shfl_xor(vs, 4, 64);
        vs += __shfl_xor(vs, 8, 64);
        const float rstd = rsqrtf(vs * (1.0f / 64.0f) + LN_EPS);

        const int node = n0 + 4 * kb + j;
        const float dd[4] = {d0, d1, d2, d3};
#pragma unroll
        for (int c = 0; c < 4; ++c) {
            float o = dd[c] * rstd * gv[c] + btv[c];
            o = o > 0.f ? o : expm1f(o);
            if (out_f) out_f[node * D + 16 * c + row] = o;
            else       out_b[node * D + 16 * c + row] = f2b(o);
        }
    }
}

static inline size_t alignup(size_t v) { return (v + 255) & ~(size_t)255; }

extern "C" void kernel_launch(void* const* d_in, const int* in_sizes, int n_in,
                              void* d_out, int out_size, void* d_ws, size_t ws_size,
                              hipStream_t stream) {
    const float* features = (const float*)d_in[0];
    const int*   src      = (const int*)d_in[1];
    const int*   dst      = (const int*)d_in[2];
    const float* Ws       = (const float*)d_in[3];
    const float* bs       = (const float*)d_in[4];
    const float* gammas   = (const float*)d_in[5];
    const float* betas    = (const float*)d_in[6];
    float* out = (float*)d_out;

    char* ws = (char*)d_ws;
    size_t off = 0;
    int* row_ptr = (int*)(ws + off); off = alignup(off + sizeof(int) * (N_NODES + 1));
    int* bcnt_g  = (int*)(ws + off); off = alignup(off + sizeof(int) * NBUCK);
    int* bbase   = (int*)(ws + off); off = alignup(off + sizeof(int) * (NBUCK + 1));
    int* bcur    = (int*)(ws + off); off = alignup(off + sizeof(int) * NBUCK);
    int2* ebuf   = (int2*)(ws + off); off = alignup(off + sizeof(int2) * (size_t)N_EDGES);
    int* ssrc    = (int*)(ws + off); off = alignup(off + sizeof(int) * N_EDGES);
    ushort* xbA  = (ushort*)(ws + off); off = alignup(off + sizeof(ushort) * (size_t)N_NODES * D);
    ushort* xbB  = (ushort*)(ws + off); off = alignup(off + sizeof(ushort) * (size_t)N_NODES * D);
    ushort* aggb = (ushort*)(ws + off); off = alignup(off + sizeof(ushort) * (size_t)N_NODES * D);
    ushort* Wperm= (ushort*)(ws + off); off = alignup(off + sizeof(ushort) * 3 * TWO_D * D);

    // --- build CSR (two-level counting sort, once) ---
    hipMemsetAsync(bcnt_g, 0, sizeof(int) * NBUCK, stream);
    bhist_kernel<<<NEB, 256, 0, stream>>>(dst, bcnt_g);
    bscan_kernel<<<1, 1024, 0, stream>>>(bcnt_g, bbase, bcur);
    bscat_kernel<<<NEB, 256, 0, stream>>>(src, dst, bcur, ebuf);
    bbuild_kernel<<<NBUCK, 256, 0, stream>>>(ebuf, bbase, row_ptr, ssrc);

    // --- converters ---
    cvt_x_kernel<<<(N_NODES * D / 4 + 255) / 256, 256, 0, stream>>>(features, xbA);
    cvt_w_kernel<<<(3 * 4 * 4 * 64 * 8 + 255) / 256, 256, 0, stream>>>(Ws, Wperm);

    // --- 3 layers ---
    const int g_blocks = N_NODES / 16;                 // 6250, quarter-wave/node
    const int m_blocks = (N_NODES / 16 + 3) / 4;       // 1563, wave/16-nodes

    ushort* xin = xbA;
    ushort* xnb[3] = { xbB, xbA, nullptr };
    for (int l = 0; l < 3; ++l) {
        gather_kernel<<<g_blocks, 256, 0, stream>>>(xin, row_ptr, ssrc, aggb);
        gemm_kernel<<<m_blocks, 256, 0, stream>>>(
            xin, aggb,
            Wperm + (size_t)l * 16 * 64 * 8,
            bs + (size_t)l * D,
            gammas + (size_t)l * D,
            betas + (size_t)l * D,
            xnb[l],
            (l == 2) ? out : nullptr);
        xin = xnb[l];
    }
}

// Round 5
// 208.699 us; speedup vs baseline: 13.5903x; 1.0358x over previous
//
#include <hip/hip_runtime.h>
#include <hip/hip_bf16.h>
#include <math.h>

#define N_NODES 100000
#define N_EDGES 1600000
#define D 64
#define TWO_D 128
#define LN_EPS 1e-5f

#define BSHIFT 7                                   // 128 nodes per bucket
#define BMASK 127
#define NBUCK ((N_NODES + 127) >> BSHIFT)          // 782
#define EPB 4096                                   // edges per block (hist/scatter)
#define NEB ((N_EDGES + EPB - 1) / EPB)            // 391
#define STAGE_CAP 4096

typedef __attribute__((ext_vector_type(4))) float f32x4;
typedef __attribute__((ext_vector_type(8))) short bf16x8;

__device__ __forceinline__ float b2f(unsigned short u) {
    return __uint_as_float(((unsigned)u) << 16);
}
__device__ __forceinline__ unsigned short f2b(float f) {
    __hip_bfloat16 h = __float2bfloat16(f);   // RNE
    return __builtin_bit_cast(unsigned short, h);
}

// ---------------------------------------------------------------------------
// CSR build, two-level counting sort (once per call; indices layer-invariant)
// Level 1: 782 buckets of 128 nodes. Level 2: per-bucket LDS counting sort.
// Edge record packed to int32: (src << 7) | (dst & 127); src < 2^17.
// ---------------------------------------------------------------------------
__global__ __launch_bounds__(256) void bhist_kernel(const int* __restrict__ dst,
                                                    int* __restrict__ bcnt_g) {
    __shared__ int h[NBUCK];
    for (int i = threadIdx.x; i < NBUCK; i += 256) h[i] = 0;
    __syncthreads();
    const int e0 = blockIdx.x * EPB;
    const int e1 = min(e0 + EPB, N_EDGES);
    for (int e = e0 + threadIdx.x; e < e1; e += 256)
        atomicAdd(&h[dst[e] >> BSHIFT], 1);
    __syncthreads();
    for (int i = threadIdx.x; i < NBUCK; i += 256)
        if (h[i]) atomicAdd(&bcnt_g[i], h[i]);
}

__global__ __launch_bounds__(1024) void bscan_kernel(const int* __restrict__ bcnt_g,
                                                     int* __restrict__ bbase,
                                                     int* __restrict__ bcur) {
    __shared__ int lds[1024];
    int v = (threadIdx.x < NBUCK) ? bcnt_g[threadIdx.x] : 0;
    lds[threadIdx.x] = v;
    __syncthreads();
    for (int off = 1; off < 1024; off <<= 1) {
        int t = (threadIdx.x >= off) ? lds[threadIdx.x - off] : 0;
        __syncthreads();
        lds[threadIdx.x] += t;
        __syncthreads();
    }
    if (threadIdx.x < NBUCK) {
        int ex = lds[threadIdx.x] - v;     // exclusive
        bbase[threadIdx.x] = ex;
        bcur[threadIdx.x] = ex;
    }
    if (threadIdx.x == 0) bbase[NBUCK] = N_EDGES;
}

// Scatter packed edges into per-bucket contiguous regions.
__global__ __launch_bounds__(512) void bscat_kernel(const int* __restrict__ src,
                                                    const int* __restrict__ dst,
                                                    int* __restrict__ bcur,
                                                    int* __restrict__ ebuf) {
    __shared__ int h[NBUCK];
    __shared__ int base[NBUCK];
    for (int i = threadIdx.x; i < NBUCK; i += 512) h[i] = 0;
    __syncthreads();
    const int e0 = blockIdx.x * EPB;
    const int e1 = min(e0 + EPB, N_EDGES);
    for (int e = e0 + threadIdx.x; e < e1; e += 512)
        atomicAdd(&h[dst[e] >> BSHIFT], 1);
    __syncthreads();
    for (int i = threadIdx.x; i < NBUCK; i += 512) {
        int c = h[i];
        if (c) base[i] = atomicAdd(&bcur[i], c);
        h[i] = 0;
    }
    __syncthreads();
    for (int e = e0 + threadIdx.x; e < e1; e += 512) {
        int d = dst[e];
        int b = d >> BSHIFT;
        int r = atomicAdd(&h[b], 1);
        ebuf[base[b] + r] = (src[e] << BSHIFT) | (d & BMASK);
    }
}

// One block per bucket: LDS counting sort by node-within-bucket; emits
// row_ptr for its 128 nodes and streams ssrc out coalesced via an LDS stage.
__global__ __launch_bounds__(512) void bbuild_kernel(const int* __restrict__ ebuf,
                                                     const int* __restrict__ bbase,
                                                     int* __restrict__ row_ptr,
                                                     int* __restrict__ ssrc) {
    __shared__ int cnt[128];
    __shared__ int excl[128];
    __shared__ int stage[STAGE_CAP];
    const int b = blockIdx.x;
    const int nb0 = b << BSHIFT;
    const int bb = bbase[b], be = bbase[b + 1];
    const int bcnt = be - bb;

    if (threadIdx.x < 128) cnt[threadIdx.x] = 0;
    __syncthreads();
    for (int i = threadIdx.x; i < bcnt; i += 512)
        atomicAdd(&cnt[ebuf[bb + i] & BMASK], 1);
    __syncthreads();

    // exclusive scan of cnt -> excl (Hillis-Steele over 128)
    int v = (threadIdx.x < 128) ? cnt[threadIdx.x] : 0;
    if (threadIdx.x < 128) excl[threadIdx.x] = v;
    __syncthreads();
    for (int off = 1; off < 128; off <<= 1) {
        int t = 0;
        if (threadIdx.x < 128 && threadIdx.x >= off) t = excl[threadIdx.x - off];
        __syncthreads();
        if (threadIdx.x < 128) excl[threadIdx.x] += t;
        __syncthreads();
    }
    if (threadIdx.x < 128) {
        excl[threadIdx.x] -= v;            // inclusive -> exclusive
        int node = nb0 + threadIdx.x;
        if (node < N_NODES) row_ptr[node] = bb + excl[threadIdx.x];
        cnt[threadIdx.x] = 0;
    }
    if (b == 0 && threadIdx.x == 0) row_ptr[N_NODES] = N_EDGES;
    __syncthreads();

    if (bcnt <= STAGE_CAP) {
        for (int i = threadIdx.x; i < bcnt; i += 512) {
            int p = ebuf[bb + i];
            int dl = p & BMASK;
            int r = atomicAdd(&cnt[dl], 1);
            stage[excl[dl] + r] = p >> BSHIFT;
        }
        __syncthreads();
        for (int i = threadIdx.x; i < bcnt; i += 512)
            ssrc[bb + i] = stage[i];
    } else {   // fallback (degree skew) — correct, uncoalesced
        for (int i = threadIdx.x; i < bcnt; i += 512) {
            int p = ebuf[bb + i];
            int dl = p & BMASK;
            int r = atomicAdd(&cnt[dl], 1);
            ssrc[bb + excl[dl] + r] = p >> BSHIFT;
        }
    }
}

// ---------------------------------------------------------------------------
// Converters
// ---------------------------------------------------------------------------
__global__ __launch_bounds__(256) void cvt_x_kernel(const float* __restrict__ xf,
                                                    ushort* __restrict__ xb) {
    int i = blockIdx.x * 256 + threadIdx.x;            // one float4 each
    if (i < N_NODES * D / 4) {
        float4 v = ((const float4*)xf)[i];
        ushort4 o;
        o.x = f2b(v.x); o.y = f2b(v.y); o.z = f2b(v.z); o.w = f2b(v.w);
        ((ushort4*)xb)[i] = o;
    }
}

// Wperm[lay][s][c][lane][j] = bf16(W[lay][32s + 8*(lane>>4) + j][16c + (lane&15)])
__global__ __launch_bounds__(256) void cvt_w_kernel(const float* __restrict__ Ws,
                                                    ushort* __restrict__ Wperm) {
    int i = blockIdx.x * 256 + threadIdx.x;
    if (i >= 3 * 4 * 4 * 64 * 8) return;
    int j    = i & 7;
    int lane = (i >> 3) & 63;
    int c    = (i >> 9) & 3;
    int s    = (i >> 11) & 3;
    int lay  = i >> 13;
    int k = 32 * s + 8 * (lane >> 4) + j;
    int d = 16 * c + (lane & 15);
    Wperm[i] = f2b(Ws[((size_t)lay * TWO_D + k) * D + d]);
}

// ---------------------------------------------------------------------------
// Gather-max kernel: quarter-wave (16 lanes) per node; register max, no
// atomics. agg = max(max_j x_src - x_dst, 0), stored bf16. 8-wide unroll.
// ---------------------------------------------------------------------------
__global__ __launch_bounds__(256) void gather_kernel(
    const ushort* __restrict__ xb,
    const int* __restrict__ row_ptr,
    const int* __restrict__ ssrc,
    ushort* __restrict__ agg)
{
    const int qw = blockIdx.x * 16 + (threadIdx.x >> 4);   // node id
    if (qw >= N_NODES) return;
    const int fl = threadIdx.x & 15;
    const int base = threadIdx.x & 48;                     // quarter-wave lane base
    const ushort4* __restrict__ x4 = (const ushort4*)xb;

    const ushort4 xs = x4[qw * 16 + fl];
    const float xd0 = b2f(xs.x), xd1 = b2f(xs.y), xd2 = b2f(xs.z), xd3 = b2f(xs.w);

    const int beg = row_ptr[qw], end = row_ptr[qw + 1];
    float m0 = -INFINITY, m1 = -INFINITY, m2 = -INFINITY, m3 = -INFINITY;

    for (int j = beg; j < end; j += 16) {
        const int cnt = min(end - j, 16);
        const int idx = ssrc[j + min(fl, cnt - 1)];
        int t = 0;
        for (; t + 8 <= cnt; t += 8) {
            int s0 = __shfl(idx, base + t,     64);
            int s1 = __shfl(idx, base + t + 1, 64);
            int s2 = __shfl(idx, base + t + 2, 64);
            int s3 = __shfl(idx, base + t + 3, 64);
            int s4 = __shfl(idx, base + t + 4, 64);
            int s5 = __shfl(idx, base + t + 5, 64);
            int s6 = __shfl(idx, base + t + 6, 64);
            int s7 = __shfl(idx, base + t + 7, 64);
            ushort4 a = x4[s0 * 16 + fl];
            ushort4 b = x4[s1 * 16 + fl];
            ushort4 c = x4[s2 * 16 + fl];
            ushort4 d = x4[s3 * 16 + fl];
            ushort4 e = x4[s4 * 16 + fl];
            ushort4 f = x4[s5 * 16 + fl];
            ushort4 g = x4[s6 * 16 + fl];
            ushort4 hh = x4[s7 * 16 + fl];
            m0 = fmaxf(m0, fmaxf(fmaxf(fmaxf(b2f(a.x), b2f(b.x)), fmaxf(b2f(c.x), b2f(d.x))),
                                 fmaxf(fmaxf(b2f(e.x), b2f(f.x)), fmaxf(b2f(g.x), b2f(hh.x)))));
            m1 = fmaxf(m1, fmaxf(fmaxf(fmaxf(b2f(a.y), b2f(b.y)), fmaxf(b2f(c.y), b2f(d.y))),
                                 fmaxf(fmaxf(b2f(e.y), b2f(f.y)), fmaxf(b2f(g.y), b2f(hh.y)))));
            m2 = fmaxf(m2, fmaxf(fmaxf(fmaxf(b2f(a.z), b2f(b.z)), fmaxf(b2f(c.z), b2f(d.z))),
                                 fmaxf(fmaxf(b2f(e.z), b2f(f.z)), fmaxf(b2f(g.z), b2f(hh.z)))));
            m3 = fmaxf(m3, fmaxf(fmaxf(fmaxf(b2f(a.w), b2f(b.w)), fmaxf(b2f(c.w), b2f(d.w))),
                                 fmaxf(fmaxf(b2f(e.w), b2f(f.w)), fmaxf(b2f(g.w), b2f(hh.w)))));
        }
        for (; t + 4 <= cnt; t += 4) {
            int s0 = __shfl(idx, base + t,     64);
            int s1 = __shfl(idx, base + t + 1, 64);
            int s2 = __shfl(idx, base + t + 2, 64);
            int s3 = __shfl(idx, base + t + 3, 64);
            ushort4 a = x4[s0 * 16 + fl];
            ushort4 b = x4[s1 * 16 + fl];
            ushort4 c = x4[s2 * 16 + fl];
            ushort4 d = x4[s3 * 16 + fl];
            m0 = fmaxf(fmaxf(m0, b2f(a.x)), fmaxf(fmaxf(b2f(b.x), b2f(c.x)), b2f(d.x)));
            m1 = fmaxf(fmaxf(m1, b2f(a.y)), fmaxf(fmaxf(b2f(b.y), b2f(c.y)), b2f(d.y)));
            m2 = fmaxf(fmaxf(m2, b2f(a.z)), fmaxf(fmaxf(b2f(b.z), b2f(c.z)), b2f(d.z)));
            m3 = fmaxf(fmaxf(m3, b2f(a.w)), fmaxf(fmaxf(b2f(b.w), b2f(c.w)), b2f(d.w)));
        }
        for (; t < cnt; ++t) {
            int s0 = __shfl(idx, base + t, 64);
            ushort4 a = x4[s0 * 16 + fl];
            m0 = fmaxf(m0, b2f(a.x));
            m1 = fmaxf(m1, b2f(a.y));
            m2 = fmaxf(m2, b2f(a.z));
            m3 = fmaxf(m3, b2f(a.w));
        }
    }

    float r0 = 0.f, r1 = 0.f, r2 = 0.f, r3 = 0.f;
    if (end > beg) {
        r0 = fmaxf(m0 - xd0, 0.f);
        r1 = fmaxf(m1 - xd1, 0.f);
        r2 = fmaxf(m2 - xd2, 0.f);
        r3 = fmaxf(m3 - xd3, 0.f);
    }
    ushort4 o;
    o.x = f2b(r0); o.y = f2b(r1); o.z = f2b(r2); o.w = f2b(r3);
    ((ushort4*)agg)[qw * 16 + fl] = o;
}

// ---------------------------------------------------------------------------
// MFMA GEMM + bias + LayerNorm + ELU. Wave per 16 nodes, 16 MFMA.
// C-layout: col = 16c + (lane&15), row = 4*(lane>>4) + j.
// ---------------------------------------------------------------------------
__global__ __launch_bounds__(256) void gemm_kernel(
    const ushort* __restrict__ xb,
    const ushort* __restrict__ agg,
    const ushort* __restrict__ Wperm,   // this layer's [4][4][64][8]
    const float* __restrict__ bias,
    const float* __restrict__ gamma,
    const float* __restrict__ beta,
    ushort* __restrict__ out_b,         // bf16 out (layers 0,1) or nullptr
    float*  __restrict__ out_f)         // f32 out (layer 2) or nullptr
{
    const int wid = (blockIdx.x * 256 + threadIdx.x) >> 6;
    if (wid >= N_NODES / 16) return;
    const int lane = threadIdx.x & 63;
    const int n0 = wid * 16;
    const int row = lane & 15;
    const int kb  = lane >> 4;

    const bf16x8* __restrict__ wp = (const bf16x8*)Wperm;
    bf16x8 wf[4][4];
#pragma unroll
    for (int s = 0; s < 4; ++s)
#pragma unroll
        for (int c = 0; c < 4; ++c)
            wf[s][c] = wp[(s * 4 + c) * 64 + lane];

    const bf16x8* __restrict__ xv = (const bf16x8*)xb;
    const bf16x8* __restrict__ av = (const bf16x8*)agg;
    bf16x8 a0 = xv[(n0 + row) * 8 + kb];
    bf16x8 a1 = xv[(n0 + row) * 8 + 4 + kb];
    bf16x8 a2 = av[(n0 + row) * 8 + kb];
    bf16x8 a3 = av[(n0 + row) * 8 + 4 + kb];

    f32x4 acc[4];
#pragma unroll
    for (int c = 0; c < 4; ++c) acc[c] = (f32x4){0.f, 0.f, 0.f, 0.f};
#pragma unroll
    for (int c = 0; c < 4; ++c) {
        acc[c] = __builtin_amdgcn_mfma_f32_16x16x32_bf16(a0, wf[0][c], acc[c], 0, 0, 0);
        acc[c] = __builtin_amdgcn_mfma_f32_16x16x32_bf16(a1, wf[1][c], acc[c], 0, 0, 0);
        acc[c] = __builtin_amdgcn_mfma_f32_16x16x32_bf16(a2, wf[2][c], acc[c], 0, 0, 0);
        acc[c] = __builtin_amdgcn_mfma_f32_16x16x32_bf16(a3, wf[3][c], acc[c], 0, 0, 0);
    }

    float bv[4], gv[4], btv[4];
#pragma unroll
    for (int c = 0; c < 4; ++c) {
        const int col = 16 * c + row;
        bv[c] = bias[col]; gv[c] = gamma[col]; btv[c] = beta[col];
    }

#pragma unroll
    for (int j = 0; j < 4; ++j) {
        float h0 = acc[0][j] + bv[0];
        float h1 = acc[1][j] + bv[1];
        float h2 = acc[2][j] + bv[2];
        float h3 = acc[3][j] + bv[3];
        float ps = (h0 + h1) + (h2 + h3);
        ps += __shfl_xor(ps, 1, 64);
        ps += __shfl_xor(ps, 2, 64);
        ps += __shfl_xor(ps, 4, 64);
        ps += __shfl_xor(ps, 8, 64);
        const float mu = ps * (1.0f / 64.0f);
        const float d0 = h0 - mu, d1 = h1 - mu, d2 = h2 - mu, d3 = h3 - mu;
        float vs = (d0 * d0 + d1 * d1) + (d2 * d2 + d3 * d3);
        vs += __shfl_xor(vs, 1, 64);
        vs += __shfl_xor(vs, 2, 64);
        vs += __shfl_xor(vs, 4, 64);
        vs += __shfl_xor(vs, 8, 64);
        const float rstd = rsqrtf(vs * (1.0f / 64.0f) + LN_EPS);

        const int node = n0 + 4 * kb + j;
        const float dd[4] = {d0, d1, d2, d3};
#pragma unroll
        for (int c = 0; c < 4; ++c) {
            float o = dd[c] * rstd * gv[c] + btv[c];
            o = o > 0.f ? o : expm1f(o);
            if (out_f) out_f[node * D + 16 * c + row] = o;
            else       out_b[node * D + 16 * c + row] = f2b(o);
        }
    }
}

static inline size_t alignup(size_t v) { return (v + 255) & ~(size_t)255; }

extern "C" void kernel_launch(void* const* d_in, const int* in_sizes, int n_in,
                              void* d_out, int out_size, void* d_ws, size_t ws_size,
                              hipStream_t stream) {
    const float* features = (const float*)d_in[0];
    const int*   src      = (const int*)d_in[1];
    const int*   dst      = (const int*)d_in[2];
    const float* Ws       = (const float*)d_in[3];
    const float* bs       = (const float*)d_in[4];
    const float* gammas   = (const float*)d_in[5];
    const float* betas    = (const float*)d_in[6];
    float* out = (float*)d_out;

    char* ws = (char*)d_ws;
    size_t off = 0;
    int* row_ptr = (int*)(ws + off); off = alignup(off + sizeof(int) * (N_NODES + 1));
    int* bcnt_g  = (int*)(ws + off); off = alignup(off + sizeof(int) * NBUCK);
    int* bbase   = (int*)(ws + off); off = alignup(off + sizeof(int) * (NBUCK + 1));
    int* bcur    = (int*)(ws + off); off = alignup(off + sizeof(int) * NBUCK);
    int* ebuf    = (int*)(ws + off); off = alignup(off + sizeof(int) * (size_t)N_EDGES);
    int* ssrc    = (int*)(ws + off); off = alignup(off + sizeof(int) * N_EDGES);
    ushort* xbA  = (ushort*)(ws + off); off = alignup(off + sizeof(ushort) * (size_t)N_NODES * D);
    ushort* xbB  = (ushort*)(ws + off); off = alignup(off + sizeof(ushort) * (size_t)N_NODES * D);
    ushort* aggb = (ushort*)(ws + off); off = alignup(off + sizeof(ushort) * (size_t)N_NODES * D);
    ushort* Wperm= (ushort*)(ws + off); off = alignup(off + sizeof(ushort) * 3 * TWO_D * D);

    // --- build CSR (two-level counting sort, once) ---
    hipMemsetAsync(bcnt_g, 0, sizeof(int) * NBUCK, stream);
    bhist_kernel<<<NEB, 256, 0, stream>>>(dst, bcnt_g);
    bscan_kernel<<<1, 1024, 0, stream>>>(bcnt_g, bbase, bcur);
    bscat_kernel<<<NEB, 512, 0, stream>>>(src, dst, bcur, ebuf);
    bbuild_kernel<<<NBUCK, 512, 0, stream>>>(ebuf, bbase, row_ptr, ssrc);

    // --- converters ---
    cvt_x_kernel<<<(N_NODES * D / 4 + 255) / 256, 256, 0, stream>>>(features, xbA);
    cvt_w_kernel<<<(3 * 4 * 4 * 64 * 8 + 255) / 256, 256, 0, stream>>>(Ws, Wperm);

    // --- 3 layers ---
    const int g_blocks = N_NODES / 16;                 // 6250, quarter-wave/node
    const int m_blocks = (N_NODES / 16 + 3) / 4;       // 1563, wave/16-nodes

    ushort* xin = xbA;
    ushort* xnb[3] = { xbB, xbA, nullptr };
    for (int l = 0; l < 3; ++l) {
        gather_kernel<<<g_blocks, 256, 0, stream>>>(xin, row_ptr, ssrc, aggb);
        gemm_kernel<<<m_blocks, 256, 0, stream>>>(
            xin, aggb,
            Wperm + (size_t)l * 16 * 64 * 8,
            bs + (size_t)l * D,
            gammas + (size_t)l * D,
            betas + (size_t)l * D,
            xnb[l],
            (l == 2) ? out : nullptr);
        xin = xnb[l];
    }
}